// Round 14
// baseline (1829.087 us; speedup 1.0000x reference)
//
#include <hip/hip_runtime.h>
#include <hip/hip_bf16.h>

typedef __attribute__((ext_vector_type(8))) short bf16x8;
typedef __attribute__((ext_vector_type(4))) float f32x4;
typedef __attribute__((ext_vector_type(2))) unsigned short u16x2;
typedef __attribute__((ext_vector_type(4))) unsigned short u16x4;
typedef __attribute__((ext_vector_type(8))) unsigned short u16x8;
typedef unsigned short u16;

#define DEV static __device__ __forceinline__

DEV float bf2f(u16 u) {
  union { unsigned int i; float f; } c; c.i = ((unsigned int)u) << 16; return c.f;
}
DEV u16 f2bf(float f) {
  union { float f; unsigned int i; } c; c.f = f;
  unsigned int i = c.i;
  i += 0x7FFFu + ((i >> 16) & 1u);   // RNE
  return (u16)(i >> 16);
}

DEV void gload_lds16(const void* g, void* l) {
  __builtin_amdgcn_global_load_lds((const __attribute__((address_space(1))) void*)g,
                                   (__attribute__((address_space(3))) void*)l, 16, 0, 0);
}

DEV f32x4 mfma16(bf16x8 a, bf16x8 b, f32x4 c) {
  return __builtin_amdgcn_mfma_f32_16x16x32_bf16(a, b, c, 0, 0, 0);
}

template<int N> DEV void vwait() { asm volatile("s_waitcnt vmcnt(%0)" :: "n"(N) : "memory"); }

// tanh-form GELU
DEV float gelu(float x) {
  float t2 = __builtin_fmaf(0.044715f * x * x, x, x);
  float e = __expf(1.5957691216f * t2);
  float th = 1.f - 2.f / (e + 1.f);
  return 0.5f * x * (1.f + th);
}

// -------- transpose+convert [Lb, K, N] fp32 -> [Lb, N, K] bf16 --------
__global__ __launch_bounds__(256) void ktranspose(const float* __restrict__ in, u16* __restrict__ out,
                                                  int K, int N) {
  __shared__ u16 tile[32][33];
  const float* src = in + (size_t)blockIdx.z * K * N;
  u16* dst = out + (size_t)blockIdx.z * K * N;
  const int n0 = blockIdx.x * 32, k0 = blockIdx.y * 32;
  const int tx = threadIdx.x, ty = threadIdx.y;
#pragma unroll
  for (int i = ty; i < 32; i += 8) tile[i][tx] = f2bf(src[(size_t)(k0 + i) * N + n0 + tx]);
  __syncthreads();
#pragma unroll
  for (int i = ty; i < 32; i += 8) dst[(size_t)(n0 + i) * K + k0 + tx] = tile[tx][i];
}

// -------- fp32 -> bf16 flat convert --------
__global__ __launch_bounds__(256) void kcvt(const float* __restrict__ in, u16* __restrict__ out, int n) {
  int i = blockIdx.x * 256 + threadIdx.x;
  if (i < n) out[i] = f2bf(in[i]);
}

// -------- cond MLP (writes bf16 h row) --------
__global__ __launch_bounds__(256) void kcond(const float* __restrict__ cond, const float* __restrict__ w1,
                                             const float* __restrict__ b1, const float* __restrict__ w2,
                                             const float* __restrict__ b2, u16* __restrict__ h) {
  __shared__ float xr[512];
  __shared__ float t1[512];
  const int b = blockIdx.x, tid = threadIdx.x;
  for (int i = tid; i < 512; i += 256) xr[i] = cond[b * 512 + i];
  __syncthreads();
  for (int j = tid; j < 512; j += 256) {
    float acc = b1[j];
    for (int k = 0; k < 512; ++k) acc += xr[k] * w1[k * 512 + j];
    t1[j] = acc / (1.f + __expf(-acc));  // silu
  }
  __syncthreads();
  for (int j = tid; j < 512; j += 256) {
    float acc = b2[j];
    for (int k = 0; k < 512; ++k) acc += t1[k] * w2[k * 512 + j];
    h[(size_t)b * 256 * 512 + j] = f2bf(acc);
  }
}

// -------- embedding (writes bf16 h) --------
__global__ __launch_bounds__(256) void kembed(const int* __restrict__ tok, const float* __restrict__ emb,
                                              const float* __restrict__ pos, u16* __restrict__ h) {
  const int idx = blockIdx.x;            // b*255 + t
  const int b = idx / 255, t = idx % 255;
  const int c = threadIdx.x * 2;
  const int tk = tok[idx];
  float2 ev = *(const float2*)(emb + (size_t)tk * 512 + c);
  float2 pv = *(const float2*)(pos + (size_t)t * 512 + c);
  u16x2 r;
  r[0] = f2bf(ev.x + pv.x);
  r[1] = f2bf(ev.y + pv.y);
  *(u16x2*)(h + ((size_t)b * 256 + 1 + t) * 512 + c) = r;
}

// -------- LayerNorm: bf16 h row -> bf16 out row, 4 rows/block --------
__global__ __launch_bounds__(256) void kln(const u16* __restrict__ hin, const float* __restrict__ g,
                                           const float* __restrict__ bt, u16* __restrict__ out) {
  const int row = blockIdx.x * 4 + (threadIdx.x >> 6), lane = threadIdx.x & 63;
  u16x8 xv = *(const u16x8*)(hin + (size_t)row * 512 + lane * 8);
  float x[8];
  float s1 = 0.f, s2 = 0.f;
#pragma unroll
  for (int j = 0; j < 8; ++j) {
    x[j] = bf2f(xv[j]);
    s1 += x[j];
    s2 += x[j] * x[j];
  }
#pragma unroll
  for (int off = 1; off < 64; off <<= 1) { s1 += __shfl_xor(s1, off); s2 += __shfl_xor(s2, off); }
  float mu = s1 * (1.f / 512.f);
  float var = s2 * (1.f / 512.f) - mu * mu;
  float rs = rsqrtf(var + 1e-5f);
  const int c0 = lane * 8;
  float4 g0 = *(const float4*)(g + c0), g1 = *(const float4*)(g + c0 + 4);
  float4 b0 = *(const float4*)(bt + c0), b1 = *(const float4*)(bt + c0 + 4);
  u16x8 o;
  o[0] = f2bf((x[0] - mu) * rs * g0.x + b0.x);
  o[1] = f2bf((x[1] - mu) * rs * g0.y + b0.y);
  o[2] = f2bf((x[2] - mu) * rs * g0.z + b0.z);
  o[3] = f2bf((x[3] - mu) * rs * g0.w + b0.w);
  o[4] = f2bf((x[4] - mu) * rs * g1.x + b1.x);
  o[5] = f2bf((x[5] - mu) * rs * g1.y + b1.y);
  o[6] = f2bf((x[6] - mu) * rs * g1.z + b1.z);
  o[7] = f2bf((x[7] - mu) * rs * g1.w + b1.w);
  *(u16x8*)(out + (size_t)row * 512 + c0) = o;
}

// ======== WIDE GEMM 128x256, BK=32, 4 waves (2x2, per-wave 64x128), 3-buf counted vmcnt ========
// MODE 0: store bf16   MODE 1: gelu->bf16
template<int MODE>
__global__ __launch_bounds__(256, 2) void kgemm3w(const u16* __restrict__ A, const u16* __restrict__ Bt,
                                                  const float* __restrict__ bias, u16* __restrict__ C,
                                                  int M, int N, int K) {
  __shared__ __align__(16) u16 As[3][4096];   // 128 rows x 64 B
  __shared__ __align__(16) u16 Bs[3][8192];   // 256 rows x 64 B
  const int tid = threadIdx.x;
  const int lane = tid & 63;
  const int wr = tid >> 7, wc = (tid >> 6) & 1;   // wave: rows wr*64, cols wc*128
  const int fr = lane & 15, fq = lane >> 4;
  const int m0 = blockIdx.x * 128, n0 = blockIdx.y * 256;
  const int nkt = K >> 5;
  const size_t Kb = (size_t)K * 2;
  const char* Ab = (const char*)A;
  const char* Bb = (const char*)Bt;

  // A staging (2 x 16B per thread), source chunk-swizzled (chunk ^= (row>>1)&3)
  const int srow = tid >> 2;
  const int sc = (tid & 3) ^ ((srow >> 1) & 3);
  const size_t a0 = (size_t)(m0 + srow) * Kb + sc * 16;
  const size_t a1 = (size_t)(m0 + srow + 64) * Kb + sc * 16;
  const int d1 = tid * 16, d2 = tid * 16 + 4096;
  // B staging (4 x 16B per thread)
  size_t bsrc[4];
  int bdst[4];
#pragma unroll
  for (int j = 0; j < 4; ++j) {
    int d = tid * 16 + j * 4096;
    int row = d >> 6, chk = (d >> 4) & 3;
    bsrc[j] = (size_t)(n0 + row) * Kb + ((chk ^ ((row >> 1) & 3)) << 4);
    bdst[j] = d;
  }

  auto stage = [&](int kt, int buf) {
    const size_t ko = (size_t)kt * 64;
    gload_lds16(Ab + a0 + ko, (char*)As[buf] + d1);
    gload_lds16(Ab + a1 + ko, (char*)As[buf] + d2);
#pragma unroll
    for (int j = 0; j < 4; ++j)
      gload_lds16(Bb + bsrc[j] + ko, (char*)Bs[buf] + bdst[j]);
  };

  f32x4 acc[4][8];
#pragma unroll
  for (int i = 0; i < 4; ++i)
#pragma unroll
    for (int j = 0; j < 8; ++j) acc[i][j] = f32x4{0.f, 0.f, 0.f, 0.f};

  stage(0, 0);
  stage(1, 1);
  vwait<6>();                                 // tile 0 landed; tile 1 in flight
  __builtin_amdgcn_s_barrier();
  __builtin_amdgcn_sched_barrier(0);

  const int kchunk = (((lane >> 4) ^ ((lane >> 1) & 3)) << 4);
  const int arow = wr * 64 + fr;
  const int brow = wc * 128 + fr;

  for (int kt = 0; kt < nkt; ++kt) {
    const int bufc = kt % 3;
    const bool deep = (kt + 2 < nkt);
    if (deep) stage(kt + 2, (kt + 2) % 3);
    const char* Ap = (const char*)As[bufc];
    const char* Bp = (const char*)Bs[bufc];
    bf16x8 aF[4], bF[8];
#pragma unroll
    for (int mt = 0; mt < 4; ++mt) aF[mt] = *(const bf16x8*)(Ap + (arow + mt * 16) * 64 + kchunk);
#pragma unroll
    for (int nt = 0; nt < 8; ++nt) bF[nt] = *(const bf16x8*)(Bp + (brow + nt * 16) * 64 + kchunk);
#pragma unroll
    for (int mt = 0; mt < 4; ++mt)
#pragma unroll
      for (int nt = 0; nt < 8; ++nt)
        acc[mt][nt] = mfma16(aF[mt], bF[nt], acc[mt][nt]);
    if (deep) vwait<6>(); else vwait<0>();
    __builtin_amdgcn_s_barrier();
    __builtin_amdgcn_sched_barrier(0);
  }

  float bv[8];
#pragma unroll
  for (int nt = 0; nt < 8; ++nt) bv[nt] = bias[n0 + wc * 128 + nt * 16 + fr];

#pragma unroll
  for (int mt = 0; mt < 4; ++mt)
#pragma unroll
    for (int r = 0; r < 4; ++r) {
      int row = m0 + wr * 64 + mt * 16 + fq * 4 + r;
      u16* cp = C + (size_t)row * N + n0 + wc * 128 + fr;
#pragma unroll
      for (int nt = 0; nt < 8; ++nt) {
        float v = acc[mt][nt][r] + bv[nt];
        if (MODE == 1) v = gelu(v);
        cp[nt * 16] = f2bf(v);
      }
    }
}

// ======== GEMM 128x128, BK=32, 3-buffer counted-vmcnt (logits only) ========
// MODE 3: logits fp32 (skip s==0 rows, col<515)
template<int MODE>
__global__ __launch_bounds__(256, 3) void kgemm3(const u16* __restrict__ A, const u16* __restrict__ Bt,
                                                 const float* __restrict__ bias, void* __restrict__ Cout,
                                                 int M, int N, int K) {
  __shared__ __align__(16) u16 As[3][4096];
  __shared__ __align__(16) u16 Bs[3][4096];
  const int tid = threadIdx.x;
  const int lane = tid & 63;
  const int wr = tid >> 7, wc = (tid >> 6) & 1;
  const int m0 = blockIdx.x * 128, n0 = blockIdx.y * 128;
  const int nkt = K >> 5;
  const size_t Kb = (size_t)K * 2;

  const int srow = tid >> 2;
  const int sc = (tid & 3) ^ ((srow >> 1) & 3);
  const int d1 = tid * 16, d2 = tid * 16 + 4096;
  int brA = n0 + srow, brB = n0 + srow + 64;
  if (MODE == 3) { brA = min(brA, N - 1); brB = min(brB, N - 1); }
  const char* Ab = (const char*)A;
  const char* Bb = (const char*)Bt;
  const size_t a0 = (size_t)(m0 + srow) * Kb + sc * 16;
  const size_t a1 = (size_t)(m0 + srow + 64) * Kb + sc * 16;
  const size_t b0 = (size_t)brA * Kb + sc * 16;
  const size_t b1 = (size_t)brB * Kb + sc * 16;

  f32x4 acc[4][4];
#pragma unroll
  for (int i = 0; i < 4; ++i)
#pragma unroll
    for (int j = 0; j < 4; ++j) acc[i][j] = f32x4{0.f, 0.f, 0.f, 0.f};

#pragma unroll
  for (int t = 0; t < 2; ++t) {
    const size_t ko = (size_t)t * 64;
    gload_lds16(Ab + a0 + ko, (char*)As[t] + d1);
    gload_lds16(Ab + a1 + ko, (char*)As[t] + d2);
    gload_lds16(Bb + b0 + ko, (char*)Bs[t] + d1);
    gload_lds16(Bb + b1 + ko, (char*)Bs[t] + d2);
  }
  asm volatile("s_waitcnt vmcnt(4)" ::: "memory");
  __builtin_amdgcn_s_barrier();
  __builtin_amdgcn_sched_barrier(0);

  const int kchunk = (((lane >> 4) ^ ((lane >> 1) & 3)) << 4);
  const int arow = wr * 64 + (lane & 15);
  const int brow = wc * 64 + (lane & 15);

  for (int kt = 0; kt < nkt; ++kt) {
    const int bufc = kt % 3;
    const bool deep = (kt + 2 < nkt);
    if (deep) {
      const int bufn = (kt + 2) % 3;
      const size_t ko = (size_t)(kt + 2) * 64;
      gload_lds16(Ab + a0 + ko, (char*)As[bufn] + d1);
      gload_lds16(Ab + a1 + ko, (char*)As[bufn] + d2);
      gload_lds16(Bb + b0 + ko, (char*)Bs[bufn] + d1);
      gload_lds16(Bb + b1 + ko, (char*)Bs[bufn] + d2);
    }
    const char* Ap = (const char*)As[bufc];
    const char* Bp = (const char*)Bs[bufc];
    bf16x8 aF[4], bF[4];
#pragma unroll
    for (int mt = 0; mt < 4; ++mt) aF[mt] = *(const bf16x8*)(Ap + (arow + mt * 16) * 64 + kchunk);
#pragma unroll
    for (int nt = 0; nt < 4; ++nt) bF[nt] = *(const bf16x8*)(Bp + (brow + nt * 16) * 64 + kchunk);
#pragma unroll
    for (int mt = 0; mt < 4; ++mt)
#pragma unroll
      for (int nt = 0; nt < 4; ++nt)
        acc[mt][nt] = mfma16(aF[mt], bF[nt], acc[mt][nt]);
    if (deep) {
      asm volatile("s_waitcnt vmcnt(4)" ::: "memory");
    } else {
      asm volatile("s_waitcnt vmcnt(0)" ::: "memory");
    }
    __builtin_amdgcn_s_barrier();
    __builtin_amdgcn_sched_barrier(0);
  }

  float* C = (float*)Cout;
#pragma unroll
  for (int mt = 0; mt < 4; ++mt)
#pragma unroll
    for (int r = 0; r < 4; ++r) {
      int row = m0 + wr * 64 + mt * 16 + (lane >> 4) * 4 + r;
      int s = row & 255;
      if (s == 0) continue;
      int bb = row >> 8;
      float* cp = C + ((size_t)bb * 255 + (s - 1)) * 515 + n0 + wc * 64 + (lane & 15);
#pragma unroll
      for (int nt = 0; nt < 4; ++nt) {
        int col = n0 + wc * 64 + nt * 16 + (lane & 15);
        if (col < 515) cp[nt * 16] = acc[mt][nt][r];
      }
    }
}

// ======== 8-phase GEMM FM=4: BM=128, BN=256, BK=64, 8 waves — MODE 2: bf16 h += ========
template<int FM>
__global__ __launch_bounds__(512, 2) void kgemm8(const u16* __restrict__ A, const u16* __restrict__ Bt,
                                                 const float* __restrict__ bias, u16* __restrict__ h,
                                                 int M, int N, int K) {
  constexpr int ABYTES = FM * 32 * 128;
  constexpr int BBYTES = 256 * 128;
  constexpr int AH = ABYTES / 2, BH = BBYTES / 2;
  constexpr int ALD = AH / 8192;
  constexpr int BOFF = 2 * ABYTES;
  constexpr int BM = FM * 32;
  __shared__ __align__(16) char shm[2 * ABYTES + 2 * BBYTES];

  const int tid = threadIdx.x;
  const int lane = tid & 63;
  const int wid = tid >> 6;
  const int wr = wid >> 2;
  const int wc = wid & 3;
  const int fr = lane & 15, fq = lane >> 4;
  const int axor = (fr & 7) << 4;
  const int m0 = blockIdx.x * BM, n0 = blockIdx.y * 256;
  const int nkt = K >> 6;
  const int Kb = K * 2;
  const char* Ab = (const char*)A;
  const char* Bb = (const char*)Bt;

  unsigned aOff[2][ALD], bOff[2][2];
#pragma unroll
  for (int hh = 0; hh < 2; ++hh) {
#pragma unroll
    for (int j = 0; j < ALD; ++j) {
      int d = hh * AH + j * 8192 + tid * 16;
      int row = d >> 7, pc = (d >> 4) & 7;
      aOff[hh][j] = (unsigned)((m0 + row) * Kb + ((pc ^ (row & 7)) << 4));
    }
#pragma unroll
    for (int j = 0; j < 2; ++j) {
      int d = hh * BH + j * 8192 + tid * 16;
      int row = d >> 7, pc = (d >> 4) & 7;
      bOff[hh][j] = (unsigned)((n0 + row) * Kb + ((pc ^ (row & 7)) << 4));
    }
  }

  auto stA = [&](int kt, int hh, int b) {
#pragma unroll
    for (int j = 0; j < ALD; ++j)
      gload_lds16(Ab + (size_t)aOff[hh][j] + (size_t)kt * 128,
                  shm + b * ABYTES + hh * AH + j * 8192 + tid * 16);
  };
  auto stB = [&](int kt, int hh, int b) {
#pragma unroll
    for (int j = 0; j < 2; ++j)
      gload_lds16(Bb + (size_t)bOff[hh][j] + (size_t)kt * 128,
                  shm + BOFF + b * BBYTES + hh * BH + j * 8192 + tid * 16);
  };
  auto rdA = [&](int b, int m, int ks) {
    return *(const bf16x8*)(shm + b * ABYTES + (wr * (BM / 2) + m * 16 + fr) * 128 +
                            ((ks * 64 + fq * 16) ^ axor));
  };
  auto rdB = [&](int b, int n, int ks) {
    return *(const bf16x8*)(shm + BOFF + b * BBYTES + (wc * 64 + n * 16 + fr) * 128 +
                            ((ks * 64 + fq * 16) ^ axor));
  };

  f32x4 acc[FM][4];
#pragma unroll
  for (int i = 0; i < FM; ++i)
#pragma unroll
    for (int j = 0; j < 4; ++j) acc[i][j] = f32x4{0.f, 0.f, 0.f, 0.f};

  stA(0, 0, 0); stA(0, 1, 0); stB(0, 0, 0); stB(0, 1, 0);
  if (nkt > 1) { stA(1, 0, 1); stA(1, 1, 1); }
  vwait<2 * ALD>();
  __builtin_amdgcn_sched_barrier(0);
  __builtin_amdgcn_s_barrier();

  for (int kt = 0; kt < nkt; ++kt) {
    const int cur = kt & 1;
    const bool sb = (kt + 1 < nkt);
    const bool sa = (kt + 2 < nkt);
    bf16x8 aF[FM][2], bF[4][2];
#pragma unroll
    for (int m = 0; m < FM; ++m) aF[m][0] = rdA(cur, m, 0);
#pragma unroll
    for (int n = 0; n < 4; ++n) bF[n][0] = rdB(cur, n, 0);
    if (sb) stB(kt + 1, 0, cur ^ 1);
    __builtin_amdgcn_s_barrier();
    __builtin_amdgcn_s_setprio(1);
#pragma unroll
    for (int m = 0; m < FM / 2; ++m)
#pragma unroll
      for (int n = 0; n < 4; ++n) acc[m][n] = mfma16(aF[m][0], bF[n][0], acc[m][n]);
    __builtin_amdgcn_s_setprio(0);
    __builtin_amdgcn_s_barrier();
#pragma unroll
    for (int m = 0; m < FM; ++m) aF[m][1] = rdA(cur, m, 1);
#pragma unroll
    for (int n = 0; n < 4; ++n) bF[n][1] = rdB(cur, n, 1);
    if (sb) stB(kt + 1, 1, cur ^ 1);
    __builtin_amdgcn_s_barrier();
    __builtin_amdgcn_s_setprio(1);
#pragma unroll
    for (int m = FM / 2; m < FM; ++m)
#pragma unroll
      for (int n = 0; n < 4; ++n) acc[m][n] = mfma16(aF[m][0], bF[n][0], acc[m][n]);
    __builtin_amdgcn_s_setprio(0);
    asm volatile("s_waitcnt lgkmcnt(0)" ::: "memory");
    __builtin_amdgcn_sched_barrier(0);
    __builtin_amdgcn_s_barrier();
    if (sa) stA(kt + 2, 0, cur);
    __builtin_amdgcn_s_barrier();
    __builtin_amdgcn_s_setprio(1);
#pragma unroll
    for (int m = 0; m < FM / 2; ++m)
#pragma unroll
      for (int n = 0; n < 4; ++n) acc[m][n] = mfma16(aF[m][1], bF[n][1], acc[m][n]);
    __builtin_amdgcn_s_setprio(0);
    __builtin_amdgcn_s_barrier();
    if (sa) stA(kt + 2, 1, cur);
    __builtin_amdgcn_s_barrier();
    __builtin_amdgcn_s_setprio(1);
#pragma unroll
    for (int m = FM / 2; m < FM; ++m)
#pragma unroll
      for (int n = 0; n < 4; ++n) acc[m][n] = mfma16(aF[m][1], bF[n][1], acc[m][n]);
    __builtin_amdgcn_s_setprio(0);
    if (sa) vwait<2 * ALD>(); else vwait<0>();
    __builtin_amdgcn_sched_barrier(0);
    __builtin_amdgcn_s_barrier();
  }

  float bv[4];
#pragma unroll
  for (int n = 0; n < 4; ++n) bv[n] = bias[n0 + wc * 64 + n * 16 + fr];

#pragma unroll
  for (int m = 0; m < FM; ++m)
#pragma unroll
    for (int r = 0; r < 4; ++r) {
      int row = m0 + wr * (BM / 2) + m * 16 + fq * 4 + r;
      u16* hp = h + (size_t)row * N + n0 + wc * 64 + fr;
#pragma unroll
      for (int n = 0; n < 4; ++n) {
        float val = acc[m][n][r] + bv[n] + bf2f(hp[n * 16]);
        hp[n * 16] = f2bf(val);
      }
    }
}

// -------- attention: per (b,h) block, 4 waves x 64 q-rows, online softmax, ----------
// -------- per-tile double-buffered K/V staging (72 KB LDS -> 2 blocks/CU) ----------
__global__ __launch_bounds__(256, 2) void kattn(const u16* __restrict__ qkv, u16* __restrict__ o) {
  __shared__ __align__(16) u16 Ks[2][64][72];
  __shared__ __align__(16) u16 Vt[2][64][72];
  __shared__ __align__(16) u16 Ps[4][64][72];
  const int tid = threadIdx.x, wv = tid >> 6, lane = tid & 63;
  const int bh = blockIdx.x, bb = bh >> 3, hh = bh & 7;
  const size_t base = (size_t)bb * 256 * 1536 + hh * 64;

  auto stage = [&](int ct, int buf) {
#pragma unroll
    for (int c = tid; c < 512; c += 256) {
      int s = c >> 3, pp = c & 7;
      int gs = ct * 64 + s;
      u16x8 kv = *(const u16x8*)(qkv + base + (size_t)gs * 1536 + 512 + pp * 8);
      *(u16x8*)&Ks[buf][s][pp * 8] = kv;
      u16x8 vv = *(const u16x8*)(qkv + base + (size_t)gs * 1536 + 1024 + pp * 8);
#pragma unroll
      for (int j = 0; j < 8; ++j) Vt[buf][pp * 8 + j][s] = vv[j];
    }
  };

  bf16x8 qf[4][2];
#pragma unroll
  for (int mt = 0; mt < 4; ++mt)
#pragma unroll
    for (int ks = 0; ks < 2; ++ks)
      qf[mt][ks] = *(const bf16x8*)(qkv + base +
                   (size_t)(wv * 64 + mt * 16 + (lane & 15)) * 1536 + ks * 32 + (lane >> 4) * 8);

  const float scale = 0.125f;
  float mrow[4][4], lsum[4][4];
#pragma unroll
  for (int mt = 0; mt < 4; ++mt)
#pragma unroll
    for (int r = 0; r < 4; ++r) { mrow[mt][r] = -1e30f; lsum[mt][r] = 0.f; }

  f32x4 oacc[4][4];
#pragma unroll
  for (int i = 0; i < 4; ++i)
#pragma unroll
    for (int j = 0; j < 4; ++j) oacc[i][j] = f32x4{0.f, 0.f, 0.f, 0.f};

  stage(0, 0);
  __syncthreads();

  for (int ct = 0; ct < 4; ++ct) {
    const int buf = ct & 1;
    if (ct + 1 < 4) stage(ct + 1, buf ^ 1);
    if (ct <= wv) {
      f32x4 sacc[4][4];
#pragma unroll
      for (int i = 0; i < 4; ++i)
#pragma unroll
        for (int j = 0; j < 4; ++j) sacc[i][j] = f32x4{0.f, 0.f, 0.f, 0.f};
#pragma unroll
      for (int ks = 0; ks < 2; ++ks) {
        bf16x8 kf[4];
#pragma unroll
        for (int nt = 0; nt < 4; ++nt)
          kf[nt] = *(const bf16x8*)&Ks[buf][nt * 16 + (lane & 15)][ks * 32 + (lane >> 4) * 8];
#pragma unroll
        for (int mt = 0; mt < 4; ++mt)
#pragma unroll
          for (int nt = 0; nt < 4; ++nt)
            sacc[mt][nt] = mfma16(qf[mt][ks], kf[nt], sacc[mt][nt]);
      }
#pragma unroll
      for (int mt = 0; mt < 4; ++mt)
#pragma unroll
        for (int r = 0; r < 4; ++r) {
          int srow = wv * 64 + mt * 16 + (lane >> 4) * 4 + r;
          float v[4];
          float mx = -1e30f;
#pragma unroll
          for (int nt = 0; nt < 4; ++nt) {
            int tcol = ct * 64 + nt * 16 + (lane & 15);
            float vv = sacc[mt][nt][r] * scale;
            v[nt] = (tcol > srow) ? -1e30f : vv;
            mx = fmaxf(mx, v[nt]);
          }
#pragma unroll
          for (int off = 1; off < 16; off <<= 1) mx = fmaxf(mx, __shfl_xor(mx, off));
          float mnew = fmaxf(mrow[mt][r], mx);
          float sf = __expf(mrow[mt][r] - mnew);
          mrow[mt][r] = mnew;
          float ps = 0.f;
#pragma unroll
          for (int nt = 0; nt < 4; ++nt) {
            float pe = (v[nt] <= -1e29f) ? 0.f : __expf(v[nt] - mnew);
            ps += pe;
            Ps[wv][mt * 16 + (lane >> 4) * 4 + r][nt * 16 + (lane & 15)] = f2bf(pe);
          }
#pragma unroll
          for (int off = 1; off < 16; off <<= 1) ps += __shfl_xor(ps, off);
          lsum[mt][r] = lsum[mt][r] * sf + ps;
#pragma unroll
          for (int nt = 0; nt < 4; ++nt) oacc[mt][nt][r] *= sf;
        }
#pragma unroll
      for (int ks = 0; ks < 2; ++ks) {
        bf16x8 pf[4], vf[4];
#pragma unroll
        for (int mt = 0; mt < 4; ++mt)
          pf[mt] = *(const bf16x8*)&Ps[wv][mt * 16 + (lane & 15)][ks * 32 + (lane >> 4) * 8];
#pragma unroll
        for (int nt = 0; nt < 4; ++nt)
          vf[nt] = *(const bf16x8*)&Vt[buf][nt * 16 + (lane & 15)][ks * 32 + (lane >> 4) * 8];
#pragma unroll
        for (int mt = 0; mt < 4; ++mt)
#pragma unroll
          for (int nt = 0; nt < 4; ++nt)
            oacc[mt][nt] = mfma16(pf[mt], vf[nt], oacc[mt][nt]);
      }
    }
    __syncthreads();
  }

#pragma unroll
  for (int mt = 0; mt < 4; ++mt)
#pragma unroll
    for (int r = 0; r < 4; ++r) {
      int s = wv * 64 + mt * 16 + (lane >> 4) * 4 + r;
      float inv = 1.f / lsum[mt][r];
      u16* op = o + ((size_t)bb * 256 + s) * 512 + hh * 64 + (lane & 15);
#pragma unroll
      for (int nt = 0; nt < 4; ++nt) op[nt * 16] = f2bf(oacc[mt][nt][r] * inv);
    }
}

// ============================== host ==============================
extern "C" void kernel_launch(void* const* d_in, const int* in_sizes, int n_in,
                              void* d_out, int out_size, void* d_ws, size_t ws_size,
                              hipStream_t stream) {
  const int* tokens = (const int*)d_in[0];
  const float* cond = (const float*)d_in[1];
  const float* emb = (const float*)d_in[2];
  const float* pos = (const float*)d_in[3];
  const float* cw1 = (const float*)d_in[4];
  const float* cb1 = (const float*)d_in[5];
  const float* cw2 = (const float*)d_in[6];
  const float* cb2 = (const float*)d_in[7];
  const float* ln1g = (const float*)d_in[8];
  const float* ln1b = (const float*)d_in[9];
  const float* qkvw = (const float*)d_in[10];
  const float* qkvb = (const float*)d_in[11];
  const float* projw = (const float*)d_in[12];
  const float* projb = (const float*)d_in[13];
  const float* ln2g = (const float*)d_in[14];
  const float* ln2b = (const float*)d_in[15];
  const float* w1 = (const float*)d_in[16];
  const float* b1 = (const float*)d_in[17];
  const float* w2 = (const float*)d_in[18];
  const float* b2 = (const float*)d_in[19];
  const float* lnfg = (const float*)d_in[20];
  const float* lnfb = (const float*)d_in[21];

  const size_t NEEDED = (size_t)16384 * 512 * 2     // h bf16
                      + (size_t)16384 * 512 * 2     // xln
                      + (size_t)16384 * 2048 * 2    // big
                      + (size_t)8 * 1536 * 512 * 2
                      + (size_t)8 * 512 * 512 * 2
                      + (size_t)8 * 2048 * 512 * 2
                      + (size_t)8 * 512 * 2048 * 2;
  if (ws_size < NEEDED) return;

  char* p = (char*)d_ws;
  u16* h = (u16*)p;            p += (size_t)16384 * 512 * 2;
  u16* xln = (u16*)p;          p += (size_t)16384 * 512 * 2;
  u16* big = (u16*)p;          p += (size_t)16384 * 2048 * 2;
  u16* attn_o = big + (size_t)16384 * 1536;
  u16* embB = big;
  u16* qkvT = (u16*)p;         p += (size_t)8 * 1536 * 512 * 2;
  u16* projT = (u16*)p;        p += (size_t)8 * 512 * 512 * 2;
  u16* w1T = (u16*)p;          p += (size_t)8 * 2048 * 512 * 2;
  u16* w2T = (u16*)p;          p += (size_t)8 * 512 * 2048 * 2;

  ktranspose<<<dim3(48, 16, 8), dim3(32, 8), 0, stream>>>(qkvw, qkvT, 512, 1536);
  ktranspose<<<dim3(16, 16, 8), dim3(32, 8), 0, stream>>>(projw, projT, 512, 512);
  ktranspose<<<dim3(64, 16, 8), dim3(32, 8), 0, stream>>>(w1, w1T, 512, 2048);
  ktranspose<<<dim3(16, 64, 8), dim3(32, 8), 0, stream>>>(w2, w2T, 2048, 512);

  kembed<<<16320, 256, 0, stream>>>(tokens, emb, pos, h);
  kcond<<<64, 256, 0, stream>>>(cond, cw1, cb1, cw2, cb2, h);

  for (int l = 0; l < 8; ++l) {
    kln<<<4096, 256, 0, stream>>>(h, ln1g + l * 512, ln1b + l * 512, xln);
    kgemm3w<0><<<dim3(128, 6), 256, 0, stream>>>(xln, qkvT + (size_t)l * 1536 * 512,
                                                 qkvb + l * 1536, big, 16384, 1536, 512);
    kattn<<<512, 256, 0, stream>>>(big, attn_o);
    kgemm8<4><<<dim3(128, 2), 512, 0, stream>>>(attn_o, projT + (size_t)l * 512 * 512,
                                                projb + l * 512, h, 16384, 512, 512);
    kln<<<4096, 256, 0, stream>>>(h, ln2g + l * 512, ln2b + l * 512, xln);
    kgemm3w<1><<<dim3(128, 8), 256, 0, stream>>>(xln, w1T + (size_t)l * 2048 * 512,
                                                 b1 + l * 2048, big, 16384, 2048, 512);
    kgemm8<4><<<dim3(128, 2), 512, 0, stream>>>(big, w2T + (size_t)l * 512 * 2048,
                                                b2 + l * 512, h, 16384, 512, 2048);
  }
  kln<<<4096, 256, 0, stream>>>(h, lnfg, lnfb, xln);
  kcvt<<<1030, 256, 0, stream>>>(emb, embB, 515 * 512);
  kgemm3<3><<<dim3(128, 5), 256, 0, stream>>>(xln, embB, nullptr, d_out, 16384, 515, 512);
}

// Round 15
// 1796.154 us; speedup vs baseline: 1.0183x; 1.0183x over previous
//
#include <hip/hip_runtime.h>
#include <hip/hip_bf16.h>

typedef __attribute__((ext_vector_type(8))) short bf16x8;
typedef __attribute__((ext_vector_type(4))) float f32x4;
typedef __attribute__((ext_vector_type(2))) unsigned short u16x2;
typedef __attribute__((ext_vector_type(4))) unsigned short u16x4;
typedef __attribute__((ext_vector_type(8))) unsigned short u16x8;
typedef unsigned short u16;

#define DEV static __device__ __forceinline__

DEV float bf2f(u16 u) {
  union { unsigned int i; float f; } c; c.i = ((unsigned int)u) << 16; return c.f;
}
DEV u16 f2bf(float f) {
  union { float f; unsigned int i; } c; c.f = f;
  unsigned int i = c.i;
  i += 0x7FFFu + ((i >> 16) & 1u);   // RNE
  return (u16)(i >> 16);
}

DEV void gload_lds16(const void* g, void* l) {
  __builtin_amdgcn_global_load_lds((const __attribute__((address_space(1))) void*)g,
                                   (__attribute__((address_space(3))) void*)l, 16, 0, 0);
}

DEV f32x4 mfma16(bf16x8 a, bf16x8 b, f32x4 c) {
  return __builtin_amdgcn_mfma_f32_16x16x32_bf16(a, b, c, 0, 0, 0);
}

template<int N> DEV void vwait() { asm volatile("s_waitcnt vmcnt(%0)" :: "n"(N) : "memory"); }

// tanh-form GELU
DEV float gelu(float x) {
  float t2 = __builtin_fmaf(0.044715f * x * x, x, x);
  float e = __expf(1.5957691216f * t2);
  float th = 1.f - 2.f / (e + 1.f);
  return 0.5f * x * (1.f + th);
}

// -------- transpose+convert [Lb, K, N] fp32 -> [Lb, N, K] bf16 --------
__global__ __launch_bounds__(256) void ktranspose(const float* __restrict__ in, u16* __restrict__ out,
                                                  int K, int N) {
  __shared__ u16 tile[32][33];
  const float* src = in + (size_t)blockIdx.z * K * N;
  u16* dst = out + (size_t)blockIdx.z * K * N;
  const int n0 = blockIdx.x * 32, k0 = blockIdx.y * 32;
  const int tx = threadIdx.x, ty = threadIdx.y;
#pragma unroll
  for (int i = ty; i < 32; i += 8) tile[i][tx] = f2bf(src[(size_t)(k0 + i) * N + n0 + tx]);
  __syncthreads();
#pragma unroll
  for (int i = ty; i < 32; i += 8) dst[(size_t)(n0 + i) * K + k0 + tx] = tile[tx][i];
}

// -------- fp32 -> bf16 flat convert --------
__global__ __launch_bounds__(256) void kcvt(const float* __restrict__ in, u16* __restrict__ out, int n) {
  int i = blockIdx.x * 256 + threadIdx.x;
  if (i < n) out[i] = f2bf(in[i]);
}

// -------- cond MLP (writes bf16 h row) --------
__global__ __launch_bounds__(256) void kcond(const float* __restrict__ cond, const float* __restrict__ w1,
                                             const float* __restrict__ b1, const float* __restrict__ w2,
                                             const float* __restrict__ b2, u16* __restrict__ h) {
  __shared__ float xr[512];
  __shared__ float t1[512];
  const int b = blockIdx.x, tid = threadIdx.x;
  for (int i = tid; i < 512; i += 256) xr[i] = cond[b * 512 + i];
  __syncthreads();
  for (int j = tid; j < 512; j += 256) {
    float acc = b1[j];
    for (int k = 0; k < 512; ++k) acc += xr[k] * w1[k * 512 + j];
    t1[j] = acc / (1.f + __expf(-acc));  // silu
  }
  __syncthreads();
  for (int j = tid; j < 512; j += 256) {
    float acc = b2[j];
    for (int k = 0; k < 512; ++k) acc += t1[k] * w2[k * 512 + j];
    h[(size_t)b * 256 * 512 + j] = f2bf(acc);
  }
}

// -------- embedding (writes bf16 h) --------
__global__ __launch_bounds__(256) void kembed(const int* __restrict__ tok, const float* __restrict__ emb,
                                              const float* __restrict__ pos, u16* __restrict__ h) {
  const int idx = blockIdx.x;            // b*255 + t
  const int b = idx / 255, t = idx % 255;
  const int c = threadIdx.x * 2;
  const int tk = tok[idx];
  float2 ev = *(const float2*)(emb + (size_t)tk * 512 + c);
  float2 pv = *(const float2*)(pos + (size_t)t * 512 + c);
  u16x2 r;
  r[0] = f2bf(ev.x + pv.x);
  r[1] = f2bf(ev.y + pv.y);
  *(u16x2*)(h + ((size_t)b * 256 + 1 + t) * 512 + c) = r;
}

// -------- LayerNorm: bf16 h row -> bf16 out row, 4 rows/block --------
__global__ __launch_bounds__(256) void kln(const u16* __restrict__ hin, const float* __restrict__ g,
                                           const float* __restrict__ bt, u16* __restrict__ out) {
  const int row = blockIdx.x * 4 + (threadIdx.x >> 6), lane = threadIdx.x & 63;
  u16x8 xv = *(const u16x8*)(hin + (size_t)row * 512 + lane * 8);
  float x[8];
  float s1 = 0.f, s2 = 0.f;
#pragma unroll
  for (int j = 0; j < 8; ++j) {
    x[j] = bf2f(xv[j]);
    s1 += x[j];
    s2 += x[j] * x[j];
  }
#pragma unroll
  for (int off = 1; off < 64; off <<= 1) { s1 += __shfl_xor(s1, off); s2 += __shfl_xor(s2, off); }
  float mu = s1 * (1.f / 512.f);
  float var = s2 * (1.f / 512.f) - mu * mu;
  float rs = rsqrtf(var + 1e-5f);
  const int c0 = lane * 8;
  float4 g0 = *(const float4*)(g + c0), g1 = *(const float4*)(g + c0 + 4);
  float4 b0 = *(const float4*)(bt + c0), b1 = *(const float4*)(bt + c0 + 4);
  u16x8 o;
  o[0] = f2bf((x[0] - mu) * rs * g0.x + b0.x);
  o[1] = f2bf((x[1] - mu) * rs * g0.y + b0.y);
  o[2] = f2bf((x[2] - mu) * rs * g0.z + b0.z);
  o[3] = f2bf((x[3] - mu) * rs * g0.w + b0.w);
  o[4] = f2bf((x[4] - mu) * rs * g1.x + b1.x);
  o[5] = f2bf((x[5] - mu) * rs * g1.y + b1.y);
  o[6] = f2bf((x[6] - mu) * rs * g1.z + b1.z);
  o[7] = f2bf((x[7] - mu) * rs * g1.w + b1.w);
  *(u16x8*)(out + (size_t)row * 512 + c0) = o;
}

// ======== GEMM 128x128, BK=32, 3-buffer counted-vmcnt, 2-way LDS swizzle ========
// MODE 0: store bf16   MODE 1: gelu->bf16   MODE 3: logits fp32 (skip s==0, col<515)
template<int MODE>
__global__ __launch_bounds__(256, 3) void kgemm3(const u16* __restrict__ A, const u16* __restrict__ Bt,
                                                 const float* __restrict__ bias, void* __restrict__ Cout,
                                                 int M, int N, int K) {
  __shared__ __align__(16) u16 As[3][4096];
  __shared__ __align__(16) u16 Bs[3][4096];
  const int tid = threadIdx.x;
  const int lane = tid & 63;
  const int wr = tid >> 7, wc = (tid >> 6) & 1;
  const int m0 = blockIdx.x * 128, n0 = blockIdx.y * 128;
  const int nkt = K >> 5;
  const size_t Kb = (size_t)K * 2;

  const int srow = tid >> 2;
  const int sc = (tid & 3) ^ ((srow >> 1) & 3);
  const int d1 = tid * 16, d2 = tid * 16 + 4096;
  int brA = n0 + srow, brB = n0 + srow + 64;
  if (MODE == 3) { brA = min(brA, N - 1); brB = min(brB, N - 1); }
  const char* Ab = (const char*)A;
  const char* Bb = (const char*)Bt;
  const size_t a0 = (size_t)(m0 + srow) * Kb + sc * 16;
  const size_t a1 = (size_t)(m0 + srow + 64) * Kb + sc * 16;
  const size_t b0 = (size_t)brA * Kb + sc * 16;
  const size_t b1 = (size_t)brB * Kb + sc * 16;

  f32x4 acc[4][4];
#pragma unroll
  for (int i = 0; i < 4; ++i)
#pragma unroll
    for (int j = 0; j < 4; ++j) acc[i][j] = f32x4{0.f, 0.f, 0.f, 0.f};

#pragma unroll
  for (int t = 0; t < 2; ++t) {
    const size_t ko = (size_t)t * 64;
    gload_lds16(Ab + a0 + ko, (char*)As[t] + d1);
    gload_lds16(Ab + a1 + ko, (char*)As[t] + d2);
    gload_lds16(Bb + b0 + ko, (char*)Bs[t] + d1);
    gload_lds16(Bb + b1 + ko, (char*)Bs[t] + d2);
  }
  asm volatile("s_waitcnt vmcnt(4)" ::: "memory");
  __builtin_amdgcn_s_barrier();
  __builtin_amdgcn_sched_barrier(0);

  const int kchunk = (((lane >> 4) ^ ((lane >> 1) & 3)) << 4);
  const int arow = wr * 64 + (lane & 15);
  const int brow = wc * 64 + (lane & 15);

  for (int kt = 0; kt < nkt; ++kt) {
    const int bufc = kt % 3;
    const bool deep = (kt + 2 < nkt);
    if (deep) {
      const int bufn = (kt + 2) % 3;
      const size_t ko = (size_t)(kt + 2) * 64;
      gload_lds16(Ab + a0 + ko, (char*)As[bufn] + d1);
      gload_lds16(Ab + a1 + ko, (char*)As[bufn] + d2);
      gload_lds16(Bb + b0 + ko, (char*)Bs[bufn] + d1);
      gload_lds16(Bb + b1 + ko, (char*)Bs[bufn] + d2);
    }
    const char* Ap = (const char*)As[bufc];
    const char* Bp = (const char*)Bs[bufc];
    bf16x8 aF[4], bF[4];
#pragma unroll
    for (int mt = 0; mt < 4; ++mt) aF[mt] = *(const bf16x8*)(Ap + (arow + mt * 16) * 64 + kchunk);
#pragma unroll
    for (int nt = 0; nt < 4; ++nt) bF[nt] = *(const bf16x8*)(Bp + (brow + nt * 16) * 64 + kchunk);
#pragma unroll
    for (int mt = 0; mt < 4; ++mt)
#pragma unroll
      for (int nt = 0; nt < 4; ++nt)
        acc[mt][nt] = mfma16(aF[mt], bF[nt], acc[mt][nt]);
    if (deep) {
      asm volatile("s_waitcnt vmcnt(4)" ::: "memory");
    } else {
      asm volatile("s_waitcnt vmcnt(0)" ::: "memory");
    }
    __builtin_amdgcn_s_barrier();
    __builtin_amdgcn_sched_barrier(0);
  }

  float bv[4];
#pragma unroll
  for (int nt = 0; nt < 4; ++nt) {
    int col = n0 + wc * 64 + nt * 16 + (lane & 15);
    bv[nt] = (MODE == 3) ? 0.f : bias[col];
  }

  if (MODE == 0 || MODE == 1) {
    u16* C = (u16*)Cout;
#pragma unroll
    for (int mt = 0; mt < 4; ++mt)
#pragma unroll
      for (int r = 0; r < 4; ++r) {
        int row = m0 + wr * 64 + mt * 16 + (lane >> 4) * 4 + r;
        u16* cp = C + (size_t)row * N + n0 + wc * 64 + (lane & 15);
#pragma unroll
        for (int nt = 0; nt < 4; ++nt) {
          float v = acc[mt][nt][r] + bv[nt];
          if (MODE == 1) v = gelu(v);
          cp[nt * 16] = f2bf(v);
        }
      }
  } else {
    float* C = (float*)Cout;
#pragma unroll
    for (int mt = 0; mt < 4; ++mt)
#pragma unroll
      for (int r = 0; r < 4; ++r) {
        int row = m0 + wr * 64 + mt * 16 + (lane >> 4) * 4 + r;
        int s = row & 255;
        if (s == 0) continue;
        int bb = row >> 8;
        float* cp = C + ((size_t)bb * 255 + (s - 1)) * 515 + n0 + wc * 64 + (lane & 15);
#pragma unroll
        for (int nt = 0; nt < 4; ++nt) {
          int col = n0 + wc * 64 + nt * 16 + (lane & 15);
          if (col < 515) cp[nt * 16] = acc[mt][nt][r];
        }
      }
  }
}

// ======== 8-phase GEMM FM=4: BM=128, BN=256, BK=64, 8 waves — MODE 2: bf16 h += ========
template<int FM>
__global__ __launch_bounds__(512, 2) void kgemm8(const u16* __restrict__ A, const u16* __restrict__ Bt,
                                                 const float* __restrict__ bias, u16* __restrict__ h,
                                                 int M, int N, int K) {
  constexpr int ABYTES = FM * 32 * 128;
  constexpr int BBYTES = 256 * 128;
  constexpr int AH = ABYTES / 2, BH = BBYTES / 2;
  constexpr int ALD = AH / 8192;
  constexpr int BOFF = 2 * ABYTES;
  constexpr int BM = FM * 32;
  __shared__ __align__(16) char shm[2 * ABYTES + 2 * BBYTES];

  const int tid = threadIdx.x;
  const int lane = tid & 63;
  const int wid = tid >> 6;
  const int wr = wid >> 2;
  const int wc = wid & 3;
  const int fr = lane & 15, fq = lane >> 4;
  const int axor = (fr & 7) << 4;
  const int m0 = blockIdx.x * BM, n0 = blockIdx.y * 256;
  const int nkt = K >> 6;
  const int Kb = K * 2;
  const char* Ab = (const char*)A;
  const char* Bb = (const char*)Bt;

  unsigned aOff[2][ALD], bOff[2][2];
#pragma unroll
  for (int hh = 0; hh < 2; ++hh) {
#pragma unroll
    for (int j = 0; j < ALD; ++j) {
      int d = hh * AH + j * 8192 + tid * 16;
      int row = d >> 7, pc = (d >> 4) & 7;
      aOff[hh][j] = (unsigned)((m0 + row) * Kb + ((pc ^ (row & 7)) << 4));
    }
#pragma unroll
    for (int j = 0; j < 2; ++j) {
      int d = hh * BH + j * 8192 + tid * 16;
      int row = d >> 7, pc = (d >> 4) & 7;
      bOff[hh][j] = (unsigned)((n0 + row) * Kb + ((pc ^ (row & 7)) << 4));
    }
  }

  auto stA = [&](int kt, int hh, int b) {
#pragma unroll
    for (int j = 0; j < ALD; ++j)
      gload_lds16(Ab + (size_t)aOff[hh][j] + (size_t)kt * 128,
                  shm + b * ABYTES + hh * AH + j * 8192 + tid * 16);
  };
  auto stB = [&](int kt, int hh, int b) {
#pragma unroll
    for (int j = 0; j < 2; ++j)
      gload_lds16(Bb + (size_t)bOff[hh][j] + (size_t)kt * 128,
                  shm + BOFF + b * BBYTES + hh * BH + j * 8192 + tid * 16);
  };
  auto rdA = [&](int b, int m, int ks) {
    return *(const bf16x8*)(shm + b * ABYTES + (wr * (BM / 2) + m * 16 + fr) * 128 +
                            ((ks * 64 + fq * 16) ^ axor));
  };
  auto rdB = [&](int b, int n, int ks) {
    return *(const bf16x8*)(shm + BOFF + b * BBYTES + (wc * 64 + n * 16 + fr) * 128 +
                            ((ks * 64 + fq * 16) ^ axor));
  };

  f32x4 acc[FM][4];
#pragma unroll
  for (int i = 0; i < FM; ++i)
#pragma unroll
    for (int j = 0; j < 4; ++j) acc[i][j] = f32x4{0.f, 0.f, 0.f, 0.f};

  stA(0, 0, 0); stA(0, 1, 0); stB(0, 0, 0); stB(0, 1, 0);
  if (nkt > 1) { stA(1, 0, 1); stA(1, 1, 1); }
  vwait<2 * ALD>();
  __builtin_amdgcn_sched_barrier(0);
  __builtin_amdgcn_s_barrier();

  for (int kt = 0; kt < nkt; ++kt) {
    const int cur = kt & 1;
    const bool sb = (kt + 1 < nkt);
    const bool sa = (kt + 2 < nkt);
    bf16x8 aF[FM][2], bF[4][2];
#pragma unroll
    for (int m = 0; m < FM; ++m) aF[m][0] = rdA(cur, m, 0);
#pragma unroll
    for (int n = 0; n < 4; ++n) bF[n][0] = rdB(cur, n, 0);
    if (sb) stB(kt + 1, 0, cur ^ 1);
    __builtin_amdgcn_s_barrier();
    __builtin_amdgcn_s_setprio(1);
#pragma unroll
    for (int m = 0; m < FM / 2; ++m)
#pragma unroll
      for (int n = 0; n < 4; ++n) acc[m][n] = mfma16(aF[m][0], bF[n][0], acc[m][n]);
    __builtin_amdgcn_s_setprio(0);
    __builtin_amdgcn_s_barrier();
#pragma unroll
    for (int m = 0; m < FM; ++m) aF[m][1] = rdA(cur, m, 1);
#pragma unroll
    for (int n = 0; n < 4; ++n) bF[n][1] = rdB(cur, n, 1);
    if (sb) stB(kt + 1, 1, cur ^ 1);
    __builtin_amdgcn_s_barrier();
    __builtin_amdgcn_s_setprio(1);
#pragma unroll
    for (int m = FM / 2; m < FM; ++m)
#pragma unroll
      for (int n = 0; n < 4; ++n) acc[m][n] = mfma16(aF[m][0], bF[n][0], acc[m][n]);
    __builtin_amdgcn_s_setprio(0);
    asm volatile("s_waitcnt lgkmcnt(0)" ::: "memory");
    __builtin_amdgcn_sched_barrier(0);
    __builtin_amdgcn_s_barrier();
    if (sa) stA(kt + 2, 0, cur);
    __builtin_amdgcn_s_barrier();
    __builtin_amdgcn_s_setprio(1);
#pragma unroll
    for (int m = 0; m < FM / 2; ++m)
#pragma unroll
      for (int n = 0; n < 4; ++n) acc[m][n] = mfma16(aF[m][1], bF[n][1], acc[m][n]);
    __builtin_amdgcn_s_setprio(0);
    __builtin_amdgcn_s_barrier();
    if (sa) stA(kt + 2, 1, cur);
    __builtin_amdgcn_s_barrier();
    __builtin_amdgcn_s_setprio(1);
#pragma unroll
    for (int m = FM / 2; m < FM; ++m)
#pragma unroll
      for (int n = 0; n < 4; ++n) acc[m][n] = mfma16(aF[m][1], bF[n][1], acc[m][n]);
    __builtin_amdgcn_s_setprio(0);
    if (sa) vwait<2 * ALD>(); else vwait<0>();
    __builtin_amdgcn_sched_barrier(0);
    __builtin_amdgcn_s_barrier();
  }

  float bv[4];
#pragma unroll
  for (int n = 0; n < 4; ++n) bv[n] = bias[n0 + wc * 64 + n * 16 + fr];

#pragma unroll
  for (int m = 0; m < FM; ++m)
#pragma unroll
    for (int r = 0; r < 4; ++r) {
      int row = m0 + wr * (BM / 2) + m * 16 + fq * 4 + r;
      u16* hp = h + (size_t)row * N + n0 + wc * 64 + fr;
#pragma unroll
      for (int n = 0; n < 4; ++n) {
        float val = acc[m][n][r] + bv[n] + bf2f(hp[n * 16]);
        hp[n * 16] = f2bf(val);
      }
    }
}

// -------- attention: per (b,h) block, 4 waves x 64 q-rows, online softmax, ----------
// -------- per-tile double-buffered K/V staging (72 KB LDS -> 2 blocks/CU) ----------
__global__ __launch_bounds__(256, 2) void kattn(const u16* __restrict__ qkv, u16* __restrict__ o) {
  __shared__ __align__(16) u16 Ks[2][64][72];
  __shared__ __align__(16) u16 Vt[2][64][72];
  __shared__ __align__(16) u16 Ps[4][64][72];
  const int tid = threadIdx.x, wv = tid >> 6, lane = tid & 63;
  const int bh = blockIdx.x, bb = bh >> 3, hh = bh & 7;
  const size_t base = (size_t)bb * 256 * 1536 + hh * 64;

  auto stage = [&](int ct, int buf) {
#pragma unroll
    for (int c = tid; c < 512; c += 256) {
      int s = c >> 3, pp = c & 7;
      int gs = ct * 64 + s;
      u16x8 kv = *(const u16x8*)(qkv + base + (size_t)gs * 1536 + 512 + pp * 8);
      *(u16x8*)&Ks[buf][s][pp * 8] = kv;
      u16x8 vv = *(const u16x8*)(qkv + base + (size_t)gs * 1536 + 1024 + pp * 8);
#pragma unroll
      for (int j = 0; j < 8; ++j) Vt[buf][pp * 8 + j][s] = vv[j];
    }
  };

  bf16x8 qf[4][2];
#pragma unroll
  for (int mt = 0; mt < 4; ++mt)
#pragma unroll
    for (int ks = 0; ks < 2; ++ks)
      qf[mt][ks] = *(const bf16x8*)(qkv + base +
                   (size_t)(wv * 64 + mt * 16 + (lane & 15)) * 1536 + ks * 32 + (lane >> 4) * 8);

  const float scale = 0.125f;
  float mrow[4][4], lsum[4][4];
#pragma unroll
  for (int mt = 0; mt < 4; ++mt)
#pragma unroll
    for (int r = 0; r < 4; ++r) { mrow[mt][r] = -1e30f; lsum[mt][r] = 0.f; }

  f32x4 oacc[4][4];
#pragma unroll
  for (int i = 0; i < 4; ++i)
#pragma unroll
    for (int j = 0; j < 4; ++j) oacc[i][j] = f32x4{0.f, 0.f, 0.f, 0.f};

  stage(0, 0);
  __syncthreads();

  for (int ct = 0; ct < 4; ++ct) {
    const int buf = ct & 1;
    if (ct + 1 < 4) stage(ct + 1, buf ^ 1);
    if (ct <= wv) {
      f32x4 sacc[4][4];
#pragma unroll
      for (int i = 0; i < 4; ++i)
#pragma unroll
        for (int j = 0; j < 4; ++j) sacc[i][j] = f32x4{0.f, 0.f, 0.f, 0.f};
#pragma unroll
      for (int ks = 0; ks < 2; ++ks) {
        bf16x8 kf[4];
#pragma unroll
        for (int nt = 0; nt < 4; ++nt)
          kf[nt] = *(const bf16x8*)&Ks[buf][nt * 16 + (lane & 15)][ks * 32 + (lane >> 4) * 8];
#pragma unroll
        for (int mt = 0; mt < 4; ++mt)
#pragma unroll
          for (int nt = 0; nt < 4; ++nt)
            sacc[mt][nt] = mfma16(qf[mt][ks], kf[nt], sacc[mt][nt]);
      }
#pragma unroll
      for (int mt = 0; mt < 4; ++mt)
#pragma unroll
        for (int r = 0; r < 4; ++r) {
          int srow = wv * 64 + mt * 16 + (lane >> 4) * 4 + r;
          float v[4];
          float mx = -1e30f;
#pragma unroll
          for (int nt = 0; nt < 4; ++nt) {
            int tcol = ct * 64 + nt * 16 + (lane & 15);
            float vv = sacc[mt][nt][r] * scale;
            v[nt] = (tcol > srow) ? -1e30f : vv;
            mx = fmaxf(mx, v[nt]);
          }
#pragma unroll
          for (int off = 1; off < 16; off <<= 1) mx = fmaxf(mx, __shfl_xor(mx, off));
          float mnew = fmaxf(mrow[mt][r], mx);
          float sf = __expf(mrow[mt][r] - mnew);
          mrow[mt][r] = mnew;
          float ps = 0.f;
#pragma unroll
          for (int nt = 0; nt < 4; ++nt) {
            float pe = (v[nt] <= -1e29f) ? 0.f : __expf(v[nt] - mnew);
            ps += pe;
            Ps[wv][mt * 16 + (lane >> 4) * 4 + r][nt * 16 + (lane & 15)] = f2bf(pe);
          }
#pragma unroll
          for (int off = 1; off < 16; off <<= 1) ps += __shfl_xor(ps, off);
          lsum[mt][r] = lsum[mt][r] * sf + ps;
#pragma unroll
          for (int nt = 0; nt < 4; ++nt) oacc[mt][nt][r] *= sf;
        }
#pragma unroll
      for (int ks = 0; ks < 2; ++ks) {
        bf16x8 pf[4], vf[4];
#pragma unroll
        for (int mt = 0; mt < 4; ++mt)
          pf[mt] = *(const bf16x8*)&Ps[wv][mt * 16 + (lane & 15)][ks * 32 + (lane >> 4) * 8];
#pragma unroll
        for (int nt = 0; nt < 4; ++nt)
          vf[nt] = *(const bf16x8*)&Vt[buf][nt * 16 + (lane & 15)][ks * 32 + (lane >> 4) * 8];
#pragma unroll
        for (int mt = 0; mt < 4; ++mt)
#pragma unroll
          for (int nt = 0; nt < 4; ++nt)
            oacc[mt][nt] = mfma16(pf[mt], vf[nt], oacc[mt][nt]);
      }
    }
    __syncthreads();
  }

#pragma unroll
  for (int mt = 0; mt < 4; ++mt)
#pragma unroll
    for (int r = 0; r < 4; ++r) {
      int s = wv * 64 + mt * 16 + (lane >> 4) * 4 + r;
      float inv = 1.f / lsum[mt][r];
      u16* op = o + ((size_t)bb * 256 + s) * 512 + hh * 64 + (lane & 15);
#pragma unroll
      for (int nt = 0; nt < 4; ++nt) op[nt * 16] = f2bf(oacc[mt][nt][r] * inv);
    }
}

// ============================== host ==============================
extern "C" void kernel_launch(void* const* d_in, const int* in_sizes, int n_in,
                              void* d_out, int out_size, void* d_ws, size_t ws_size,
                              hipStream_t stream) {
  const int* tokens = (const int*)d_in[0];
  const float* cond = (const float*)d_in[1];
  const float* emb = (const float*)d_in[2];
  const float* pos = (const float*)d_in[3];
  const float* cw1 = (const float*)d_in[4];
  const float* cb1 = (const float*)d_in[5];
  const float* cw2 = (const float*)d_in[6];
  const float* cb2 = (const float*)d_in[7];
  const float* ln1g = (const float*)d_in[8];
  const float* ln1b = (const float*)d_in[9];
  const float* qkvw = (const float*)d_in[10];
  const float* qkvb = (const float*)d_in[11];
  const float* projw = (const float*)d_in[12];
  const float* projb = (const float*)d_in[13];
  const float* ln2g = (const float*)d_in[14];
  const float* ln2b = (const float*)d_in[15];
  const float* w1 = (const float*)d_in[16];
  const float* b1 = (const float*)d_in[17];
  const float* w2 = (const float*)d_in[18];
  const float* b2 = (const float*)d_in[19];
  const float* lnfg = (const float*)d_in[20];
  const float* lnfb = (const float*)d_in[21];

  const size_t NEEDED = (size_t)16384 * 512 * 2     // h bf16
                      + (size_t)16384 * 512 * 2     // xln
                      + (size_t)16384 * 2048 * 2    // big
                      + (size_t)8 * 1536 * 512 * 2
                      + (size_t)8 * 512 * 512 * 2
                      + (size_t)8 * 2048 * 512 * 2
                      + (size_t)8 * 512 * 2048 * 2;
  if (ws_size < NEEDED) return;

  char* p = (char*)d_ws;
  u16* h = (u16*)p;            p += (size_t)16384 * 512 * 2;
  u16* xln = (u16*)p;          p += (size_t)16384 * 512 * 2;
  u16* big = (u16*)p;          p += (size_t)16384 * 2048 * 2;
  u16* attn_o = big + (size_t)16384 * 1536;
  u16* embB = big;
  u16* qkvT = (u16*)p;         p += (size_t)8 * 1536 * 512 * 2;
  u16* projT = (u16*)p;        p += (size_t)8 * 512 * 512 * 2;
  u16* w1T = (u16*)p;          p += (size_t)8 * 2048 * 512 * 2;
  u16* w2T = (u16*)p;          p += (size_t)8 * 512 * 2048 * 2;

  ktranspose<<<dim3(48, 16, 8), dim3(32, 8), 0, stream>>>(qkvw, qkvT, 512, 1536);
  ktranspose<<<dim3(16, 16, 8), dim3(32, 8), 0, stream>>>(projw, projT, 512, 512);
  ktranspose<<<dim3(64, 16, 8), dim3(32, 8), 0, stream>>>(w1, w1T, 512, 2048);
  ktranspose<<<dim3(16, 64, 8), dim3(32, 8), 0, stream>>>(w2, w2T, 2048, 512);

  kembed<<<16320, 256, 0, stream>>>(tokens, emb, pos, h);
  kcond<<<64, 256, 0, stream>>>(cond, cw1, cb1, cw2, cb2, h);

  for (int l = 0; l < 8; ++l) {
    kln<<<4096, 256, 0, stream>>>(h, ln1g + l * 512, ln1b + l * 512, xln);
    kgemm3<0><<<dim3(128, 12), 256, 0, stream>>>(xln, qkvT + (size_t)l * 1536 * 512,
                                                 qkvb + l * 1536, big, 16384, 1536, 512);
    kattn<<<512, 256, 0, stream>>>(big, attn_o);
    kgemm8<4><<<dim3(128, 2), 512, 0, stream>>>(attn_o, projT + (size_t)l * 512 * 512,
                                                projb + l * 512, h, 16384, 512, 512);
    kln<<<4096, 256, 0, stream>>>(h, ln2g + l * 512, ln2b + l * 512, xln);
    kgemm3<1><<<dim3(128, 16), 256, 0, stream>>>(xln, w1T + (size_t)l * 2048 * 512,
                                                 b1 + l * 2048, big, 16384, 2048, 512);
    kgemm8<4><<<dim3(128, 2), 512, 0, stream>>>(big, w2T + (size_t)l * 512 * 2048,
                                                b2 + l * 512, h, 16384, 512, 2048);
  }
  kln<<<4096, 256, 0, stream>>>(h, lnfg, lnfb, xln);
  kcvt<<<1030, 256, 0, stream>>>(emb, embB, 515 * 512);
  kgemm3<3><<<dim3(128, 5), 256, 0, stream>>>(xln, embB, nullptr, d_out, 16384, 515, 512);
}